// Round 5
// baseline (397.928 us; speedup 1.0000x reference)
//
#include <hip/hip_runtime.h>

typedef unsigned short ushort_t;
typedef __attribute__((ext_vector_type(8))) __bf16 bf16x8;
typedef __attribute__((ext_vector_type(4))) float f32x4;

#define NT 8192     // tokens
#define NE 8        // experts
#define ND 1024     // model dim
#define NF 4096     // ffn dim
#define CAP 1280    // capacity per expert
#define KSPLIT 4    // split-K for GEMM2 (K=1024 per block)

// Blocked operand layout: per expert, elem (row, k) lives at [(k>>6)][row][k&63]
// so one 256-row x 64-k A-tile (32KB) / 128-row (16KB) B-tile is contiguous.

// ws layout (bytes)
#define W1T_OFF 0u                       // 8*4096*1024*2 = 67108864
#define W2T_OFF 67108864u                // 67108864
#define XD_OFF  134217728u               // 10240*1024*2 = 20971520
#define H_OFF   155189248u               // 10240*4096*2 = 83886080
#define EIDX_OFF 239075328u              // 8192*4
#define TPROB_OFF 239108096u             // 8192*4
#define TSLOT_OFF 239140864u             // 10240*4  -> total 239181824

#define SLOT_BYTES 49152                 // A 32KB + B 16KB per K-tile slot, 3 slots

__device__ __forceinline__ unsigned short f2bf(float f) {
  unsigned int u = __float_as_uint(f);
  unsigned int r = (u + 0x7fffu + ((u >> 16) & 1u)) >> 16;
  return (unsigned short)r;
}

// ---------------- zero out ----------------
__global__ void zero_kernel(float* __restrict__ p, long n) {
  long i = (long)blockIdx.x * blockDim.x + threadIdx.x;
  long stride = (long)gridDim.x * blockDim.x;
  float4* p4 = (float4*)p;
  long n4 = n >> 2;
  for (long j = i; j < n4; j += stride) p4[j] = make_float4(0.f, 0.f, 0.f, 0.f);
}

// ---------------- routing: one wave per token ----------------
__global__ void route_kernel(const float* __restrict__ x, const float* __restrict__ gw,
                             const float* __restrict__ gb, int* __restrict__ eidx,
                             float* __restrict__ tprob) {
  int wid = threadIdx.x >> 6, lane = threadIdx.x & 63;
  int t = blockIdx.x * 4 + wid;
  const float4* xv = (const float4*)(x + (size_t)t * ND);
  float acc[NE];
#pragma unroll
  for (int e = 0; e < NE; ++e) acc[e] = 0.f;
#pragma unroll
  for (int c = 0; c < 4; ++c) {
    float4 xx = xv[lane * 4 + c];
#pragma unroll
    for (int e = 0; e < NE; ++e) {
      float4 wv = *(const float4*)(gw + (size_t)e * ND + lane * 16 + c * 4);
      acc[e] += xx.x * wv.x + xx.y * wv.y + xx.z * wv.z + xx.w * wv.w;
    }
  }
#pragma unroll
  for (int off = 32; off >= 1; off >>= 1) {
#pragma unroll
    for (int e = 0; e < NE; ++e) acc[e] += __shfl_xor(acc[e], off, 64);
  }
  if (lane == 0) {
    float l[NE];
#pragma unroll
    for (int e = 0; e < NE; ++e) l[e] = acc[e] + gb[e];
    float mx = l[0];
    int am = 0;
#pragma unroll
    for (int e = 1; e < NE; ++e) {
      if (l[e] > mx) { mx = l[e]; am = e; }   // first occurrence kept on ties
    }
    float s = 0.f;
#pragma unroll
    for (int e = 0; e < NE; ++e) s += __expf(l[e] - mx);
    eidx[t] = am;
    tprob[t] = 1.0f / s;   // softmax prob of the max logit
  }
}

// ---------------- capacity scan (single block, order-preserving, wave-shuffle) ----------------
__global__ void scan_kernel(const int* __restrict__ eidx, int* __restrict__ tslot) {
  __shared__ unsigned long long w0[16], w1[16];
  int tid = threadIdx.x;
  int lane = tid & 63, wid = tid >> 6;
  for (int i = tid; i < NE * CAP; i += 1024) tslot[i] = -1;
  int myE[8];
  unsigned long long a = 0, b = 0;
#pragma unroll
  for (int i = 0; i < 8; ++i) {
    int e = eidx[tid * 8 + i];
    myE[i] = e;
    if (e < 4) a += 1ULL << (16 * e);
    else       b += 1ULL << (16 * (e - 4));
  }
  unsigned long long ia = a, ib = b;
#pragma unroll
  for (int off = 1; off < 64; off <<= 1) {
    unsigned long long pa = __shfl_up(ia, off, 64);
    unsigned long long pb = __shfl_up(ib, off, 64);
    if (lane >= off) { ia += pa; ib += pb; }
  }
  if (lane == 63) { w0[wid] = ia; w1[wid] = ib; }
  __syncthreads();
  if (wid == 0 && lane < 16) {
    unsigned long long va = w0[lane], vb = w1[lane];
#pragma unroll
    for (int off = 1; off < 16; off <<= 1) {
      unsigned long long pa = __shfl_up(va, off, 64);
      unsigned long long pb = __shfl_up(vb, off, 64);
      if (lane >= off) { va += pa; vb += pb; }
    }
    w0[lane] = va; w1[lane] = vb;
  }
  __syncthreads();
  unsigned long long ea = ia - a, eb = ib - b;
  if (wid > 0) { ea += w0[wid - 1]; eb += w1[wid - 1]; }
  int base[NE];
#pragma unroll
  for (int e = 0; e < 4; ++e) {
    base[e]     = (int)((ea >> (16 * e)) & 0xffffULL);
    base[4 + e] = (int)((eb >> (16 * e)) & 0xffffULL);
  }
#pragma unroll
  for (int i = 0; i < 8; ++i) {
    int t = tid * 8 + i;
    int e = myE[i];
    int p = base[e]++;
    if (p < CAP) tslot[e * CAP + p] = t;
  }
}

// ---------------- gather tokens -> bf16 dispatch buffer (blocked layout) ----------------
__global__ void gather_kernel(const float* __restrict__ x, const int* __restrict__ tslot,
                              ushort_t* __restrict__ Xd) {
  int slot = blockIdx.x;
  int e = slot / CAP, row = slot % CAP;
  int t = tslot[slot];
  int d = threadIdx.x * 4;
  ushort4 u;
  if (t >= 0) {
    float4 v = *(const float4*)(x + (size_t)t * ND + d);
    u.x = f2bf(v.x); u.y = f2bf(v.y); u.z = f2bf(v.z); u.w = f2bf(v.w);
  } else {
    u.x = 0; u.y = 0; u.z = 0; u.w = 0;
  }
  ushort_t* dst = Xd + (size_t)e * CAP * ND + (size_t)(d >> 6) * CAP * 64 + row * 64 + (d & 63);
  *(ushort4*)dst = u;
}

// ---------------- transpose+convert: W [E][K][N] fp32 -> Wt_b [E][K/64][N][64] bf16 ----------------
__global__ void transpose_kernel(const float* __restrict__ W, ushort_t* __restrict__ Wt,
                                 int K, int N) {
  __shared__ float tile[64][65];
  int e = blockIdx.z;
  int n0 = blockIdx.x * 64, k0 = blockIdx.y * 64;
  const float* We = W + (size_t)e * K * N;
  ushort_t* Wte = Wt + (size_t)e * K * N + (size_t)(k0 >> 6) * N * 64;
  for (int i = threadIdx.x; i < 1024; i += 256) {
    int r = i >> 4, c4 = (i & 15) << 2;
    float4 v = *(const float4*)(We + (size_t)(k0 + r) * N + n0 + c4);
    tile[r][c4] = v.x; tile[r][c4 + 1] = v.y; tile[r][c4 + 2] = v.z; tile[r][c4 + 3] = v.w;
  }
  __syncthreads();
  for (int i = threadIdx.x; i < 512; i += 256) {
    int n = i >> 3, kq = (i & 7) << 3;
    uint4 u;
    u.x = (unsigned)f2bf(tile[kq + 0][n]) | ((unsigned)f2bf(tile[kq + 1][n]) << 16);
    u.y = (unsigned)f2bf(tile[kq + 2][n]) | ((unsigned)f2bf(tile[kq + 3][n]) << 16);
    u.z = (unsigned)f2bf(tile[kq + 4][n]) | ((unsigned)f2bf(tile[kq + 5][n]) << 16);
    u.w = (unsigned)f2bf(tile[kq + 6][n]) | ((unsigned)f2bf(tile[kq + 7][n]) << 16);
    *(uint4*)(Wte + (size_t)(n0 + n) * 64 + kq) = u;
  }
}

// ---------------- staging: one K-tile slot = A[256][64] (32KB) + B[128][64] (16KB) ----------------
__device__ __forceinline__ void stageA(const char* src, char* sA, int tid) {
#pragma unroll
  for (int r = 0; r < 4; ++r) {
    int o = r * 8192 + tid * 16;
    int row = o >> 7;
    int s = (o & ~127) | ((o & 127) ^ ((row & 7) << 4));   // pre-swizzled source
    __builtin_amdgcn_global_load_lds((const __attribute__((address_space(1))) void*)(src + s),
                                     (__attribute__((address_space(3))) void*)(sA + o),
                                     16, 0, 0);
  }
}
__device__ __forceinline__ void stageB(const char* src, char* sB, int tid) {
#pragma unroll
  for (int r = 0; r < 2; ++r) {
    int o = r * 8192 + tid * 16;
    int row = o >> 7;
    int s = (o & ~127) | ((o & 127) ^ ((row & 7) << 4));
    __builtin_amdgcn_global_load_lds((const __attribute__((address_space(1))) void*)(src + s),
                                     (__attribute__((address_space(3))) void*)(sB + o),
                                     16, 0, 0);
  }
}

// ---------------- GEMM mainloop: 3-slot ring, counted vmcnt(6), raw s_barrier ----------------
// BM=256 x BN=128, BK=64, 8 waves (4Mx2N), per-wave 64x64 output (acc[4][4]).
// Tile t computed while t+1 ready and t+2 in flight (6 loads/thread). Boundary waits
// vmcnt(6): FIFO retirement guarantees tile t+1 landed when <=6 remain.
__device__ __forceinline__ void gemm_mainloop(const char* __restrict__ aP,
                                              const char* __restrict__ bP,
                                              int nkt, size_t aBlkB, size_t bBlkB,
                                              char* smem, f32x4 acc[4][4]) {
  const int tid = threadIdx.x;
  const int lane = tid & 63, wid = tid >> 6;
  const int wr = wid >> 1, wc = wid & 1;        // 4x2 wave grid
  const int lr = lane & 15, lq = lane >> 4;

  auto phase = [&](char* sA, char* sB, int kk) {
    const int kbyte = kk * 64 + lq * 16;
    bf16x8 av[4], bv[4];
#pragma unroll
    for (int m = 0; m < 4; ++m) {
      int row = wr * 64 + m * 16 + lr;
      av[m] = *(const bf16x8*)(sA + ((((row << 7) + kbyte)) ^ ((lr & 7) << 4)));
    }
#pragma unroll
    for (int n = 0; n < 4; ++n) {
      int row = wc * 64 + n * 16 + lr;
      bv[n] = *(const bf16x8*)(sB + ((((row << 7) + kbyte)) ^ ((lr & 7) << 4)));
    }
    asm volatile("s_waitcnt lgkmcnt(0)");
    __builtin_amdgcn_s_setprio(1);
#pragma unroll
    for (int m = 0; m < 4; ++m)
#pragma unroll
      for (int n = 0; n < 4; ++n)
        acc[m][n] = __builtin_amdgcn_mfma_f32_16x16x32_bf16(av[m], bv[n], acc[m][n], 0, 0, 0);
    __builtin_amdgcn_s_setprio(0);
  };

  // prologue: stage tiles 0 and 1
  stageA(aP, smem, tid);
  stageB(bP, smem + 32768, tid);
  if (nkt > 1) {
    stageA(aP + aBlkB, smem + SLOT_BYTES, tid);
    stageB(bP + bBlkB, smem + SLOT_BYTES + 32768, tid);
    asm volatile("s_waitcnt vmcnt(6)" ::: "memory");   // tile0 landed, tile1 in flight
  } else {
    asm volatile("s_waitcnt vmcnt(0)" ::: "memory");
  }
  __builtin_amdgcn_s_barrier();

  const char* aNext = aP + 2 * aBlkB;
  const char* bNext = bP + 2 * bBlkB;
  for (int t = 0; t < nkt; ++t) {
    int cur = t % 3;
    int nslot = (t + 2) % 3;
    bool pf = (t + 2) < nkt;
    char* sA = smem + cur * SLOT_BYTES;
    char* sB = sA + 32768;
    // phase 0: issue A(t+2) prefetch, compute kk0
    if (pf) stageA(aNext, smem + nslot * SLOT_BYTES, tid);
    __builtin_amdgcn_s_barrier();
    phase(sA, sB, 0);
    // phase 1: issue B(t+2) prefetch, compute kk1
    if (pf) stageB(bNext, smem + nslot * SLOT_BYTES + 32768, tid);
    __builtin_amdgcn_s_barrier();
    phase(sA, sB, 1);
    // K-tile boundary: ensure tile t+1 fully landed; keep t+2's 6 loads in flight
    if (t + 1 < nkt) {
      if (pf) asm volatile("s_waitcnt vmcnt(6)" ::: "memory");
      else    asm volatile("s_waitcnt vmcnt(0)" ::: "memory");
    }
    __builtin_amdgcn_s_barrier();
    aNext += aBlkB; bNext += bBlkB;
  }
}

// ---------------- GEMM1: H_b = relu(Xd_b @ W1t_b^T + b1), bf16 blocked out ----------------
// grid 1280 = 5m x 32n x 8e; expert = bid&7 (one expert per XCD), m-fastest in-XCD.
__global__ __launch_bounds__(512, 1) void gemm1_kernel(const ushort_t* __restrict__ Xd,
                                                       const ushort_t* __restrict__ W1t,
                                                       const float* __restrict__ b1,
                                                       ushort_t* __restrict__ H) {
  int e = blockIdx.x & 7;
  int idx = blockIdx.x >> 3;          // 0..159
  int bn0 = (idx / 5) * 128;
  int bm0 = (idx % 5) * 256;
  const char* A = (const char*)(Xd + (size_t)e * CAP * ND) + (size_t)bm0 * 128;
  const char* B = (const char*)(W1t + (size_t)e * NF * ND) + (size_t)bn0 * 128;
  __shared__ __align__(16) char smem[3 * SLOT_BYTES];
  f32x4 zero4 = {0.f, 0.f, 0.f, 0.f};
  f32x4 acc[4][4];
#pragma unroll
  for (int m = 0; m < 4; ++m)
#pragma unroll
    for (int n = 0; n < 4; ++n) acc[m][n] = zero4;
  gemm_mainloop(A, B, ND / 64, (size_t)CAP * 128, (size_t)NF * 128, smem, acc);
  const int lane = threadIdx.x & 63, wid = threadIdx.x >> 6;
  const int wr = wid >> 1, wc = wid & 1;
  const int lr = lane & 15, lq = lane >> 4;
  ushort_t* He = H + (size_t)e * CAP * NF;
#pragma unroll
  for (int m = 0; m < 4; ++m) {
#pragma unroll
    for (int n = 0; n < 4; ++n) {
      int col = bn0 + wc * 64 + n * 16 + lr;
      float bias = b1[(size_t)e * NF + col];
      ushort_t* dst = He + (size_t)(col >> 6) * CAP * 64 + (col & 63);
#pragma unroll
      for (int j = 0; j < 4; ++j) {
        int row = bm0 + wr * 64 + m * 16 + lq * 4 + j;
        float v = acc[m][n][j] + bias;
        v = fmaxf(v, 0.f);
        dst[(size_t)row * 64] = f2bf(v);
      }
    }
  }
}

// ---------------- GEMM2 (split-K=4): out[token] += (H_b @ W2t_b^T [+ b2]) * tprob ----------------
// grid 1280 = 5m x 8n x 4s x 8e; expert = bid&7.
__global__ __launch_bounds__(512, 1) void gemm2_kernel(const ushort_t* __restrict__ H,
                                                       const ushort_t* __restrict__ W2t,
                                                       const float* __restrict__ b2,
                                                       const int* __restrict__ tslot,
                                                       const float* __restrict__ tprob,
                                                       float* __restrict__ out) {
  int e = blockIdx.x & 7;
  int idx = blockIdx.x >> 3;          // 0..159
  int s = idx / 40;                   // 0..3
  int r2 = idx % 40;
  int bn0 = (r2 / 5) * 128;
  int bm0 = (r2 % 5) * 256;
  const int kbQ = NF / 64 / KSPLIT;   // 16
  const char* A = (const char*)(H + (size_t)e * CAP * NF) + (size_t)(s * kbQ) * CAP * 128 + (size_t)bm0 * 128;
  const char* B = (const char*)(W2t + (size_t)e * ND * NF) + (size_t)(s * kbQ) * ND * 128 + (size_t)bn0 * 128;
  __shared__ __align__(16) char smem[3 * SLOT_BYTES];
  f32x4 zero4 = {0.f, 0.f, 0.f, 0.f};
  f32x4 acc[4][4];
#pragma unroll
  for (int m = 0; m < 4; ++m)
#pragma unroll
    for (int n = 0; n < 4; ++n) acc[m][n] = zero4;
  gemm_mainloop(A, B, kbQ, (size_t)CAP * 128, (size_t)ND * 128, smem, acc);
  const int lane = threadIdx.x & 63, wid = threadIdx.x >> 6;
  const int wr = wid >> 1, wc = wid & 1;
  const int lr = lane & 15, lq = lane >> 4;
  float bias[4];
#pragma unroll
  for (int n = 0; n < 4; ++n)
    bias[n] = (s == 0) ? b2[(size_t)e * ND + bn0 + wc * 64 + n * 16 + lr] : 0.f;
#pragma unroll
  for (int m = 0; m < 4; ++m) {
#pragma unroll
    for (int j = 0; j < 4; ++j) {
      int row = bm0 + wr * 64 + m * 16 + lq * 4 + j;
      int t = tslot[e * CAP + row];
      if (t >= 0) {
        float p = tprob[t];
#pragma unroll
        for (int n = 0; n < 4; ++n) {
          int col = bn0 + wc * 64 + n * 16 + lr;
          unsafeAtomicAdd(&out[(size_t)t * ND + col], (acc[m][n][j] + bias[n]) * p);
        }
      }
    }
  }
}

extern "C" void kernel_launch(void* const* d_in, const int* in_sizes, int n_in,
                              void* d_out, int out_size, void* d_ws, size_t ws_size,
                              hipStream_t stream) {
  const float* h  = (const float*)d_in[0];
  const float* gw = (const float*)d_in[1];
  const float* gb = (const float*)d_in[2];
  const float* w1 = (const float*)d_in[3];
  const float* b1 = (const float*)d_in[4];
  const float* w2 = (const float*)d_in[5];
  const float* b2 = (const float*)d_in[6];
  float* out = (float*)d_out;
  char* ws = (char*)d_ws;

  ushort_t* W1t = (ushort_t*)(ws + W1T_OFF);
  ushort_t* W2t = (ushort_t*)(ws + W2T_OFF);
  ushort_t* Xd  = (ushort_t*)(ws + XD_OFF);
  ushort_t* H   = (ushort_t*)(ws + H_OFF);
  int* eidx     = (int*)(ws + EIDX_OFF);
  float* tprob  = (float*)(ws + TPROB_OFF);
  int* tslot    = (int*)(ws + TSLOT_OFF);

  zero_kernel<<<1024, 256, 0, stream>>>(out, (long)out_size);
  route_kernel<<<NT / 4, 256, 0, stream>>>(h, gw, gb, eidx, tprob);
  scan_kernel<<<1, 1024, 0, stream>>>(eidx, tslot);
  gather_kernel<<<NE * CAP, 256, 0, stream>>>(h, tslot, Xd);
  transpose_kernel<<<dim3(NF / 64, ND / 64, NE), 256, 0, stream>>>(w1, W1t, ND, NF);
  transpose_kernel<<<dim3(ND / 64, NF / 64, NE), 256, 0, stream>>>(w2, W2t, NF, ND);
  gemm1_kernel<<<(CAP / 256) * (NF / 128) * NE, 512, 0, stream>>>(Xd, W1t, b1, H);
  gemm2_kernel<<<(CAP / 256) * (ND / 128) * NE * KSPLIT, 512, 0, stream>>>(H, W2t, b2, tslot, tprob, out);
}

// Round 6
// 384.396 us; speedup vs baseline: 1.0352x; 1.0352x over previous
//
#include <hip/hip_runtime.h>

typedef unsigned short ushort_t;
typedef __attribute__((ext_vector_type(8))) __bf16 bf16x8;
typedef __attribute__((ext_vector_type(4))) float f32x4;

#define NT 8192     // tokens
#define NE 8        // experts
#define ND 1024     // model dim
#define NF 4096     // ffn dim
#define CAP 1280    // capacity per expert
#define KSPLIT 2    // split-K for GEMM2 (K=2048 per block)

// Blocked operand layout (BK=32): per expert, elem (row,k) at [(k>>5)][row][k&31]
// -> one k-block row = 64B contiguous.

// ws layout (bytes)
#define W1T_OFF 0u
#define W2T_OFF 67108864u
#define XD_OFF  134217728u
#define H_OFF   155189248u
#define EIDX_OFF 239075328u
#define TPROB_OFF 239108096u
#define TSLOT_OFF 239140864u

#define NSLOT 6
#define SLOT_B 24576     // A 16KB + B 8KB

__device__ __forceinline__ unsigned short f2bf(float f) {
  unsigned int u = __float_as_uint(f);
  unsigned int r = (u + 0x7fffu + ((u >> 16) & 1u)) >> 16;
  return (unsigned short)r;
}

// ---------------- zero out ----------------
__global__ void zero_kernel(float* __restrict__ p, long n) {
  long i = (long)blockIdx.x * blockDim.x + threadIdx.x;
  long stride = (long)gridDim.x * blockDim.x;
  float4* p4 = (float4*)p;
  long n4 = n >> 2;
  for (long j = i; j < n4; j += stride) p4[j] = make_float4(0.f, 0.f, 0.f, 0.f);
}

// ---------------- routing: one wave per token ----------------
__global__ void route_kernel(const float* __restrict__ x, const float* __restrict__ gw,
                             const float* __restrict__ gb, int* __restrict__ eidx,
                             float* __restrict__ tprob) {
  int wid = threadIdx.x >> 6, lane = threadIdx.x & 63;
  int t = blockIdx.x * 4 + wid;
  const float4* xv = (const float4*)(x + (size_t)t * ND);
  float acc[NE];
#pragma unroll
  for (int e = 0; e < NE; ++e) acc[e] = 0.f;
#pragma unroll
  for (int c = 0; c < 4; ++c) {
    float4 xx = xv[lane * 4 + c];
#pragma unroll
    for (int e = 0; e < NE; ++e) {
      float4 wv = *(const float4*)(gw + (size_t)e * ND + lane * 16 + c * 4);
      acc[e] += xx.x * wv.x + xx.y * wv.y + xx.z * wv.z + xx.w * wv.w;
    }
  }
#pragma unroll
  for (int off = 32; off >= 1; off >>= 1) {
#pragma unroll
    for (int e = 0; e < NE; ++e) acc[e] += __shfl_xor(acc[e], off, 64);
  }
  if (lane == 0) {
    float l[NE];
#pragma unroll
    for (int e = 0; e < NE; ++e) l[e] = acc[e] + gb[e];
    float mx = l[0];
    int am = 0;
#pragma unroll
    for (int e = 1; e < NE; ++e) {
      if (l[e] > mx) { mx = l[e]; am = e; }
    }
    float s = 0.f;
#pragma unroll
    for (int e = 0; e < NE; ++e) s += __expf(l[e] - mx);
    eidx[t] = am;
    tprob[t] = 1.0f / s;
  }
}

// ---------------- capacity scan (single block, order-preserving, wave-shuffle) ----------------
__global__ void scan_kernel(const int* __restrict__ eidx, int* __restrict__ tslot) {
  __shared__ unsigned long long w0[16], w1[16];
  int tid = threadIdx.x;
  int lane = tid & 63, wid = tid >> 6;
  for (int i = tid; i < NE * CAP; i += 1024) tslot[i] = -1;
  int myE[8];
  unsigned long long a = 0, b = 0;
#pragma unroll
  for (int i = 0; i < 8; ++i) {
    int e = eidx[tid * 8 + i];
    myE[i] = e;
    if (e < 4) a += 1ULL << (16 * e);
    else       b += 1ULL << (16 * (e - 4));
  }
  unsigned long long ia = a, ib = b;
#pragma unroll
  for (int off = 1; off < 64; off <<= 1) {
    unsigned long long pa = __shfl_up(ia, off, 64);
    unsigned long long pb = __shfl_up(ib, off, 64);
    if (lane >= off) { ia += pa; ib += pb; }
  }
  if (lane == 63) { w0[wid] = ia; w1[wid] = ib; }
  __syncthreads();
  if (wid == 0 && lane < 16) {
    unsigned long long va = w0[lane], vb = w1[lane];
#pragma unroll
    for (int off = 1; off < 16; off <<= 1) {
      unsigned long long pa = __shfl_up(va, off, 64);
      unsigned long long pb = __shfl_up(vb, off, 64);
      if (lane >= off) { va += pa; vb += pb; }
    }
    w0[lane] = va; w1[lane] = vb;
  }
  __syncthreads();
  unsigned long long ea = ia - a, eb = ib - b;
  if (wid > 0) { ea += w0[wid - 1]; eb += w1[wid - 1]; }
  int base[NE];
#pragma unroll
  for (int e = 0; e < 4; ++e) {
    base[e]     = (int)((ea >> (16 * e)) & 0xffffULL);
    base[4 + e] = (int)((eb >> (16 * e)) & 0xffffULL);
  }
#pragma unroll
  for (int i = 0; i < 8; ++i) {
    int t = tid * 8 + i;
    int e = myE[i];
    int p = base[e]++;
    if (p < CAP) tslot[e * CAP + p] = t;
  }
}

// ---------------- gather tokens -> bf16 dispatch buffer (blocked-32) ----------------
__global__ void gather_kernel(const float* __restrict__ x, const int* __restrict__ tslot,
                              ushort_t* __restrict__ Xd) {
  int slot = blockIdx.x;
  int e = slot / CAP, row = slot % CAP;
  int t = tslot[slot];
  int d = threadIdx.x * 4;
  ushort4 u;
  if (t >= 0) {
    float4 v = *(const float4*)(x + (size_t)t * ND + d);
    u.x = f2bf(v.x); u.y = f2bf(v.y); u.z = f2bf(v.z); u.w = f2bf(v.w);
  } else {
    u.x = 0; u.y = 0; u.z = 0; u.w = 0;
  }
  ushort_t* dst = Xd + (size_t)e * CAP * ND + (size_t)(d >> 5) * CAP * 32 + row * 32 + (d & 31);
  *(ushort4*)dst = u;
}

// ---------------- transpose+convert: W [E][K][N] fp32 -> Wt blocked-32 bf16 ----------------
__global__ void transpose_kernel(const float* __restrict__ W, ushort_t* __restrict__ Wt,
                                 int K, int N) {
  __shared__ float tile[64][65];
  int e = blockIdx.z;
  int n0 = blockIdx.x * 64, k0 = blockIdx.y * 64;
  const float* We = W + (size_t)e * K * N;
  ushort_t* Wte = Wt + (size_t)e * K * N;
  for (int i = threadIdx.x; i < 1024; i += 256) {
    int r = i >> 4, c4 = (i & 15) << 2;
    float4 v = *(const float4*)(We + (size_t)(k0 + r) * N + n0 + c4);
    tile[r][c4] = v.x; tile[r][c4 + 1] = v.y; tile[r][c4 + 2] = v.z; tile[r][c4 + 3] = v.w;
  }
  __syncthreads();
  for (int i = threadIdx.x; i < 512; i += 256) {
    int n = i >> 3, kq = (i & 7) << 3;       // kq in {0,8,...,56}
    uint4 u;
    u.x = (unsigned)f2bf(tile[kq + 0][n]) | ((unsigned)f2bf(tile[kq + 1][n]) << 16);
    u.y = (unsigned)f2bf(tile[kq + 2][n]) | ((unsigned)f2bf(tile[kq + 3][n]) << 16);
    u.z = (unsigned)f2bf(tile[kq + 4][n]) | ((unsigned)f2bf(tile[kq + 5][n]) << 16);
    u.w = (unsigned)f2bf(tile[kq + 6][n]) | ((unsigned)f2bf(tile[kq + 7][n]) << 16);
    size_t dst = (size_t)((k0 + kq) >> 5) * N * 32 + (size_t)(n0 + n) * 32 + (kq & 31);
    *(uint4*)(Wte + dst) = u;
  }
}

// ---------------- staging one ring slot: A[256][32] + B[128][32], packed LDS ----------------
// LDS row = 128B holds global rows (r, r+128) [A] or (r, r+64) [B]; XOR ((row&7)<<4)
// applied via pre-swizzled global source (linear LDS dest for global_load_lds).
__device__ __forceinline__ void stage_slot(const char* slabA, const char* slabB,
                                           char* smem, int slot, int tid) {
  char* sA = smem + slot * SLOT_B;
  char* sB = sA + 16384;
#pragma unroll
  for (int r = 0; r < 2; ++r) {
    int o = r * 8192 + tid * 16;
    int Lrow = o >> 7;
    int inner = (o & 127) ^ ((Lrow & 7) << 4);
    int grow = ((inner >> 6) << 7) | Lrow;
    __builtin_amdgcn_global_load_lds(
        (const __attribute__((address_space(1))) void*)(slabA + grow * 64 + (inner & 63)),
        (__attribute__((address_space(3))) void*)(sA + o), 16, 0, 0);
  }
  {
    int o = tid * 16;
    int Lrow = o >> 7;
    int inner = (o & 127) ^ ((Lrow & 7) << 4);
    int grow = ((inner >> 6) << 6) | Lrow;
    __builtin_amdgcn_global_load_lds(
        (const __attribute__((address_space(1))) void*)(slabB + grow * 64 + (inner & 63)),
        (__attribute__((address_space(3))) void*)(sB + o), 16, 0, 0);
  }
}

// ---------------- GEMM mainloop: 6-slot ring, stage 5 ahead, vmcnt(9), 1 barrier/slot ----
// BM=256 x BN=128, BK=32, 8 waves (4Mx2N), per-wave 64x64 (acc[4][4], 16 MFMA/slot).
// ds_reads fetch slot s+1's fragments (ping-pong regs) while MFMA consumes slot s.
__device__ __forceinline__ void gemm_mainloop(const char* __restrict__ slabA,
                                              const char* __restrict__ slabB,
                                              int nkt, size_t aBlk, size_t bBlk,
                                              char* smem, f32x4 acc[4][4]) {
  const int tid = threadIdx.x;
  const int lane = tid & 63, wid = tid >> 6;
  const int wr = wid >> 1, wc = wid & 1;
  const int lr = lane & 15, lq = lane >> 4;

  int aOff[4], bOff[4];
#pragma unroll
  for (int m = 0; m < 4; ++m) {
    int grow = wr * 64 + m * 16 + lr;
    int Lrow = grow & 127, h = grow >> 7;
    aOff[m] = Lrow * 128 + ((h * 64 + lq * 16) ^ ((lr & 7) << 4));
  }
#pragma unroll
  for (int n = 0; n < 4; ++n) {
    int Lrow = n * 16 + lr;
    bOff[n] = 16384 + Lrow * 128 + ((wc * 64 + lq * 16) ^ ((lr & 7) << 4));
  }

  // prologue: stage slots 0..4; ensure 0,1 landed (vmcnt 9 = slots 2,3,4 outstanding)
#pragma unroll
  for (int i = 0; i < 5; ++i)
    stage_slot(slabA + (size_t)i * aBlk, slabB + (size_t)i * bBlk, smem, i, tid);
  asm volatile("s_waitcnt vmcnt(9)" ::: "memory");
  __builtin_amdgcn_s_barrier();

  bf16x8 aC[4], bC[4], aN[4], bN[4];
#pragma unroll
  for (int m = 0; m < 4; ++m) aC[m] = *(const bf16x8*)(smem + aOff[m]);
#pragma unroll
  for (int n = 0; n < 4; ++n) bC[n] = *(const bf16x8*)(smem + bOff[n]);

  auto body = [&](int s, bf16x8 (&cA)[4], bf16x8 (&cB)[4],
                  bf16x8 (&nA)[4], bf16x8 (&nB)[4]) {
    if (s + 5 < nkt)
      stage_slot(slabA + (size_t)(s + 5) * aBlk, slabB + (size_t)(s + 5) * bBlk,
                 smem, (s + 5) % NSLOT, tid);
    if (s + 1 < nkt) {
      char* base = smem + ((s + 1) % NSLOT) * SLOT_B;
#pragma unroll
      for (int m = 0; m < 4; ++m) nA[m] = *(const bf16x8*)(base + aOff[m]);
#pragma unroll
      for (int n = 0; n < 4; ++n) nB[n] = *(const bf16x8*)(base + bOff[n]);
    }
    __builtin_amdgcn_s_setprio(1);
#pragma unroll
    for (int m = 0; m < 4; ++m)
#pragma unroll
      for (int n = 0; n < 4; ++n)
        acc[m][n] = __builtin_amdgcn_mfma_f32_16x16x32_bf16(cA[m], cB[n], acc[m][n], 0, 0, 0);
    __builtin_amdgcn_s_setprio(0);
    // boundary: ensure slot s+2 landed; keep s+3..s+5 (up to 9 loads) in flight
    int rem = nkt - s - 3;
    if (rem >= 3)      asm volatile("s_waitcnt vmcnt(9)" ::: "memory");
    else if (rem == 2) asm volatile("s_waitcnt vmcnt(6)" ::: "memory");
    else if (rem == 1) asm volatile("s_waitcnt vmcnt(3)" ::: "memory");
    else               asm volatile("s_waitcnt vmcnt(0)" ::: "memory");
    __builtin_amdgcn_s_barrier();
  };

  for (int s = 0; s < nkt; s += 2) {
    body(s,     aC, bC, aN, bN);
    body(s + 1, aN, bN, aC, bC);
  }
}

// ---------------- GEMM1: H_b = relu(Xd_b @ W1t_b^T + b1) ----------------
// grid 1280 = 8e x (32n x 5m); e = bid&7 pins one expert per XCD; m-fastest.
__global__ __launch_bounds__(512, 1) void gemm1_kernel(const ushort_t* __restrict__ Xd,
                                                       const ushort_t* __restrict__ W1t,
                                                       const float* __restrict__ b1,
                                                       ushort_t* __restrict__ H) {
  int e = blockIdx.x & 7;
  int idx = blockIdx.x >> 3;          // 0..159
  int bn0 = (idx / 5) * 128;
  int bm0 = (idx % 5) * 256;
  const char* slabA = (const char*)(Xd + (size_t)e * CAP * ND) + (size_t)bm0 * 64;
  const char* slabB = (const char*)(W1t + (size_t)e * NF * ND) + (size_t)bn0 * 64;
  __shared__ __align__(16) char smem[NSLOT * SLOT_B];
  f32x4 zero4 = {0.f, 0.f, 0.f, 0.f};
  f32x4 acc[4][4];
#pragma unroll
  for (int m = 0; m < 4; ++m)
#pragma unroll
    for (int n = 0; n < 4; ++n) acc[m][n] = zero4;
  gemm_mainloop(slabA, slabB, ND / 32, (size_t)CAP * 64, (size_t)NF * 64, smem, acc);
  const int lane = threadIdx.x & 63, wid = threadIdx.x >> 6;
  const int wr = wid >> 1, wc = wid & 1;
  const int lr = lane & 15, lq = lane >> 4;
  ushort_t* He = H + (size_t)e * CAP * NF;
#pragma unroll
  for (int m = 0; m < 4; ++m) {
#pragma unroll
    for (int n = 0; n < 4; ++n) {
      int col = bn0 + wc * 64 + n * 16 + lr;
      float bias = b1[(size_t)e * NF + col];
      ushort_t* dst = He + (size_t)(col >> 5) * (CAP * 32) + (col & 31);
#pragma unroll
      for (int j = 0; j < 4; ++j) {
        int row = bm0 + wr * 64 + m * 16 + lq * 4 + j;
        float v = acc[m][n][j] + bias;
        v = fmaxf(v, 0.f);
        dst[(size_t)row * 32] = f2bf(v);
      }
    }
  }
}

// ---------------- GEMM2 (split-K=2): out[token] += (H_b @ W2t_b^T [+ b2]) * tprob ----
// grid 640 = 8e x (2s x 8n x 5m); K=2048 per block (64 slots).
__global__ __launch_bounds__(512, 1) void gemm2_kernel(const ushort_t* __restrict__ H,
                                                       const ushort_t* __restrict__ W2t,
                                                       const float* __restrict__ b2,
                                                       const int* __restrict__ tslot,
                                                       const float* __restrict__ tprob,
                                                       float* __restrict__ out) {
  int e = blockIdx.x & 7;
  int idx = blockIdx.x >> 3;          // 0..79
  int s = idx / 40;
  int r2 = idx % 40;
  int bn0 = (r2 / 5) * 128;
  int bm0 = (r2 % 5) * 256;
  const int kbQ = NF / 32 / KSPLIT;   // 64 k-blocks per split
  const char* slabA = (const char*)(H + (size_t)e * CAP * NF)
                      + (size_t)(s * kbQ) * CAP * 64 + (size_t)bm0 * 64;
  const char* slabB = (const char*)(W2t + (size_t)e * ND * NF)
                      + (size_t)(s * kbQ) * ND * 64 + (size_t)bn0 * 64;
  __shared__ __align__(16) char smem[NSLOT * SLOT_B];
  f32x4 zero4 = {0.f, 0.f, 0.f, 0.f};
  f32x4 acc[4][4];
#pragma unroll
  for (int m = 0; m < 4; ++m)
#pragma unroll
    for (int n = 0; n < 4; ++n) acc[m][n] = zero4;
  gemm_mainloop(slabA, slabB, kbQ, (size_t)CAP * 64, (size_t)ND * 64, smem, acc);
  const int lane = threadIdx.x & 63, wid = threadIdx.x >> 6;
  const int wr = wid >> 1, wc = wid & 1;
  const int lr = lane & 15, lq = lane >> 4;
  float bias[4];
#pragma unroll
  for (int n = 0; n < 4; ++n)
    bias[n] = (s == 0) ? b2[(size_t)e * ND + bn0 + wc * 64 + n * 16 + lr] : 0.f;
#pragma unroll
  for (int m = 0; m < 4; ++m) {
#pragma unroll
    for (int j = 0; j < 4; ++j) {
      int row = bm0 + wr * 64 + m * 16 + lq * 4 + j;
      int t = tslot[e * CAP + row];
      if (t >= 0) {
        float p = tprob[t];
#pragma unroll
        for (int n = 0; n < 4; ++n) {
          int col = bn0 + wc * 64 + n * 16 + lr;
          unsafeAtomicAdd(&out[(size_t)t * ND + col], (acc[m][n][j] + bias[n]) * p);
        }
      }
    }
  }
}

extern "C" void kernel_launch(void* const* d_in, const int* in_sizes, int n_in,
                              void* d_out, int out_size, void* d_ws, size_t ws_size,
                              hipStream_t stream) {
  const float* h  = (const float*)d_in[0];
  const float* gw = (const float*)d_in[1];
  const float* gb = (const float*)d_in[2];
  const float* w1 = (const float*)d_in[3];
  const float* b1 = (const float*)d_in[4];
  const float* w2 = (const float*)d_in[5];
  const float* b2 = (const float*)d_in[6];
  float* out = (float*)d_out;
  char* ws = (char*)d_ws;

  ushort_t* W1t = (ushort_t*)(ws + W1T_OFF);
  ushort_t* W2t = (ushort_t*)(ws + W2T_OFF);
  ushort_t* Xd  = (ushort_t*)(ws + XD_OFF);
  ushort_t* H   = (ushort_t*)(ws + H_OFF);
  int* eidx     = (int*)(ws + EIDX_OFF);
  float* tprob  = (float*)(ws + TPROB_OFF);
  int* tslot    = (int*)(ws + TSLOT_OFF);

  zero_kernel<<<1024, 256, 0, stream>>>(out, (long)out_size);
  route_kernel<<<NT / 4, 256, 0, stream>>>(h, gw, gb, eidx, tprob);
  scan_kernel<<<1, 1024, 0, stream>>>(eidx, tslot);
  gather_kernel<<<NE * CAP, 256, 0, stream>>>(h, tslot, Xd);
  transpose_kernel<<<dim3(NF / 64, ND / 64, NE), 256, 0, stream>>>(w1, W1t, ND, NF);
  transpose_kernel<<<dim3(ND / 64, NF / 64, NE), 256, 0, stream>>>(w2, W2t, NF, ND);
  gemm1_kernel<<<(CAP / 256) * (NF / 128) * NE, 512, 0, stream>>>(Xd, W1t, b1, H);
  gemm2_kernel<<<(CAP / 256) * (ND / 128) * NE * KSPLIT, 512, 0, stream>>>(H, W2t, b2, tslot, tprob, out);
}